// Round 7
// baseline (145.286 us; speedup 1.0000x reference)
//
#include <hip/hip_runtime.h>
#include <hip/hip_cooperative_groups.h>
#include <math.h>

#define Bb 64
#define Ss 512
#define Hh 768
#define Ll 9
#define CCH 16      // chunks per batch
#define TCH 32      // steps per chunk
#define NROWS (Bb * Ss)
#define SMEM_BYTES 27648   // max(W stage 6912 floats, CRF arrays ~26.9 KB)

namespace cg = cooperative_groups;

// ---- DPP add helper: v += dpp_perm(v), inactive source lanes contribute 0 ----
template<int CTRL>
__device__ __forceinline__ float dpp_add(float v) {
    int r = __builtin_amdgcn_update_dpp(0, __float_as_int(v), CTRL, 0xF, 0xF, true);
    return v + __int_as_float(r);
}

// ---------------- emissions phase: wave-per-row GEMV ----------------
// W staged into LDS coalesced (once per block), per-lane 108-reg fragment
// (pre-scaled by class_weights), DPP wave reduction, lane 63 stores.
__device__ __forceinline__ void emis_phase(
    const float* __restrict__ hs, const float* __restrict__ W,
    const float* __restrict__ bvec, const float* __restrict__ cw,
    float* __restrict__ emis, int wave, int nwav)
{
    extern __shared__ char smem[];
    float* wl = (float*)smem;
    const int tid  = threadIdx.x;
    const int lane = tid & 63;

    // stage W (768*9 floats = 27648 B) coalesced into LDS
    {
        const float4* src = (const float4*)W;
        float4* dst = (float4*)wl;
        for (int i = tid; i < (Hh * Ll) / 4; i += 256) dst[i] = src[i];
    }
    __syncthreads();

    // per-lane fragment: w[j][e*9+l] = W[(j*256 + lane*4 + e)*9 + l] * cw[l]
    float w[3][36];
    {
        const float* p = wl + lane * 36;
#pragma unroll
        for (int j = 0; j < 3; ++j)
#pragma unroll
            for (int i = 0; i < 36; ++i) w[j][i] = p[j * 2304 + i];
    }
    float b2[Ll];
#pragma unroll
    for (int l = 0; l < Ll; ++l) {
        const float c = cw[l];
        b2[l] = bvec[l] * c;
#pragma unroll
        for (int j = 0; j < 3; ++j)
#pragma unroll
            for (int e = 0; e < 4; ++e) w[j][e * 9 + l] *= c;
    }

    for (int row = wave; row < NROWS; row += nwav) {
        const float4* rp = (const float4*)(hs + (size_t)row * Hh);
        const float4 x0 = rp[lane], x1 = rp[64 + lane], x2 = rp[128 + lane];
        float acc[Ll];
#pragma unroll
        for (int l = 0; l < Ll; ++l) acc[l] = 0.f;
#pragma unroll
        for (int l = 0; l < Ll; ++l) {
            acc[l] = fmaf(x0.x, w[0][0 * 9 + l], acc[l]);
            acc[l] = fmaf(x0.y, w[0][1 * 9 + l], acc[l]);
            acc[l] = fmaf(x0.z, w[0][2 * 9 + l], acc[l]);
            acc[l] = fmaf(x0.w, w[0][3 * 9 + l], acc[l]);
            acc[l] = fmaf(x1.x, w[1][0 * 9 + l], acc[l]);
            acc[l] = fmaf(x1.y, w[1][1 * 9 + l], acc[l]);
            acc[l] = fmaf(x1.z, w[1][2 * 9 + l], acc[l]);
            acc[l] = fmaf(x1.w, w[1][3 * 9 + l], acc[l]);
            acc[l] = fmaf(x2.x, w[2][0 * 9 + l], acc[l]);
            acc[l] = fmaf(x2.y, w[2][1 * 9 + l], acc[l]);
            acc[l] = fmaf(x2.z, w[2][2 * 9 + l], acc[l]);
            acc[l] = fmaf(x2.w, w[2][3 * 9 + l], acc[l]);
        }
        // DPP wave64 reduction: after 6 stages lane 63 holds the full sum
#pragma unroll
        for (int l = 0; l < Ll; ++l) {
            float v = acc[l];
            v = dpp_add<0x111>(v);   // row_shr:1
            v = dpp_add<0x112>(v);   // row_shr:2
            v = dpp_add<0x114>(v);   // row_shr:4
            v = dpp_add<0x118>(v);   // row_shr:8  -> lane15 of each 16-row
            v = dpp_add<0x142>(v);   // row_bcast:15 -> lane31, lane63 partials
            v = dpp_add<0x143>(v);   // row_bcast:31 -> lane63 = full sum
            acc[l] = v;
        }
        if (lane == 63) {
            float* o = emis + (size_t)row * Ll;
#pragma unroll
            for (int l = 0; l < Ll; ++l) o[l] = acc[l] + b2[l];
        }
    }
}

// ---------------- CRF phase for one batch (256 threads) ----------------
__device__ __forceinline__ void crf_batch(
    int b, const float* __restrict__ emis, const int* __restrict__ labels,
    const int* __restrict__ attn, const float* __restrict__ trans,
    const float* __restrict__ startt, const float* __restrict__ endt,
    float* __restrict__ out)
{
    extern __shared__ char smem[];
    int*   mkt_s    = (int*)smem;                  // 512 ints   @ 0
    float* emis_s   = (float*)(smem + 2048);       // 4608 f     @ 2048
    float* trans_s  = (float*)(smem + 20480);      // 81 f
    float* et_s     = (float*)(smem + 20804);      // 81 f
    float* erow_s   = (float*)(smem + 21128);      // 1296 f
    float* rowmax_s = (float*)(smem + 26312);      // 144 f
    float* num_s    = (float*)(smem + 26888);      // 1 f

    const int tid = threadIdx.x;

    // ---- stage ----
#pragma unroll
    for (int it = 0; it < 2; ++it) {
        const int t = tid + it * 256;
        const int lab = labels[b * Ss + t];
        const int att = attn[b * Ss + t];
        const int tag = (lab == -100) ? 0 : lab;
        const int mk  = ((lab != -100) && (att == 1)) ? 1 : 0;
        mkt_s[t] = tag | (mk << 4);
    }
    {
        const float4* src = (const float4*)(emis + (size_t)b * Ss * Ll);
        float4* dst = (float4*)emis_s;
        for (int i = tid; i < (Ss * Ll) / 4; i += 256) dst[i] = src[i];
    }
    if (tid < Ll * Ll) {
        const float tv = trans[tid];
        trans_s[tid] = tv;
        et_s[tid] = __expf(tv);
    }
    __syncthreads();

    // ---- chunk workers: tid < 144; row i of chunk c's 9x9 transfer matrix ----
    if (tid < CCH * Ll) {
        const int i = tid % Ll;
        const int c = tid / Ll;
        float et[Ll][Ll];
#pragma unroll
        for (int l = 0; l < Ll; ++l)
#pragma unroll
            for (int k = 0; k < Ll; ++k) et[l][k] = et_s[l * Ll + k];
        float vv[Ll];
#pragma unroll
        for (int l = 0; l < Ll; ++l) vv[l] = (l == i) ? 0.f : -1e30f;
        for (int s = (c == 0 ? 1 : 0); s < TCH; ++s) {
            const int t = c * TCH + s;
            const int mv = mkt_s[t];
            if (mv >> 4) {
                const float* e = emis_s + t * Ll;
                float m = vv[0];
#pragma unroll
                for (int l = 1; l < Ll; ++l) m = fmaxf(m, vv[l]);
                float p[Ll];
#pragma unroll
                for (int l = 0; l < Ll; ++l) p[l] = __expf(vv[l] - m);
                float nv[Ll];
#pragma unroll
                for (int k = 0; k < Ll; ++k) {
                    float sacc = 0.f;
#pragma unroll
                    for (int l = 0; l < Ll; ++l) sacc = fmaf(p[l], et[l][k], sacc);
                    nv[k] = m + __logf(sacc) + e[k];
                }
#pragma unroll
                for (int l = 0; l < Ll; ++l) vv[l] = nv[l];
            }
        }
        float m = vv[0];
#pragma unroll
        for (int l = 1; l < Ll; ++l) m = fmaxf(m, vv[l]);
        rowmax_s[c * Ll + i] = m;
#pragma unroll
        for (int l = 0; l < Ll; ++l)
            erow_s[(c * Ll + i) * Ll + l] = __expf(vv[l] - m);
    }

    // ---- numerator: wave 3 (tid 192..255) ----
    if (tid >= 192) {
        const int lane = tid - 192;
        float psum = 0.f;
        int pcnt = 0;
        for (int t = lane; t < Ss; t += 64) {
            const int mv  = mkt_s[t];
            const int tag = mv & 15;
            const bool mk = (mv >> 4) || (t == 0);
            if (t >= 1 && (mv >> 4)) {
                const int tagp = mkt_s[t - 1] & 15;
                psum += trans_s[tagp * Ll + tag] + emis_s[t * Ll + tag];
            }
            pcnt += mk ? 1 : 0;
        }
#pragma unroll
        for (int off = 32; off; off >>= 1) {
            psum += __shfl_xor(psum, off);
            pcnt += __shfl_xor(pcnt, off);
        }
        if (lane == 0) {
            const int tag0 = mkt_s[0] & 15;
            const int tagL = mkt_s[pcnt - 1] & 15;
            num_s[0] = startt[tag0] + emis_s[tag0] + psum + endt[tagL];
        }
    }
    __syncthreads();

    // ---- compose: lanes 0..8 of wave 0 (lane k owns column k) ----
    if (tid < Ll) {
        const int lane = tid;
        float sc[Ll];
#pragma unroll
        for (int l = 0; l < Ll; ++l) sc[l] = startt[l] + emis_s[l];
        for (int c = 0; c < CCH; ++c) {
            float u[Ll];
#pragma unroll
            for (int l = 0; l < Ll; ++l) u[l] = sc[l] + rowmax_s[c * Ll + l];
            float M = u[0];
#pragma unroll
            for (int l = 1; l < Ll; ++l) M = fmaxf(M, u[l]);
            float sacc = 0.f;
#pragma unroll
            for (int l = 0; l < Ll; ++l)
                sacc = fmaf(__expf(u[l] - M), erow_s[(c * Ll + l) * Ll + lane], sacc);
            const float ns = M + __logf(sacc);
#pragma unroll
            for (int l = 0; l < Ll; ++l) sc[l] = __shfl(ns, l);
        }
        float M2 = sc[0] + endt[0];
#pragma unroll
        for (int l = 1; l < Ll; ++l) M2 = fmaxf(M2, sc[l] + endt[l]);
        float s2 = 0.f;
#pragma unroll
        for (int l = 0; l < Ll; ++l) s2 += __expf(sc[l] + endt[l] - M2);
        if (lane == 0) {
            const float logz = M2 + __logf(s2);
            atomicAdd(out, -(num_s[0] - logz) * (1.f / Bb));
        }
    }
}

// ---------------- single cooperative kernel ----------------
__global__ __launch_bounds__(256, 3) void k_fused(
    const float* __restrict__ hs, const float* __restrict__ W,
    const float* __restrict__ bvec, const float* __restrict__ cw,
    const float* __restrict__ startt, const float* __restrict__ endt,
    const float* __restrict__ trans, const int* __restrict__ labels,
    const int* __restrict__ attn, float* __restrict__ emis,
    float* __restrict__ out)
{
    const int wave = blockIdx.x * 4 + (threadIdx.x >> 6);
    emis_phase(hs, W, bvec, cw, emis, wave, gridDim.x * 4);
    if (blockIdx.x == 0 && threadIdx.x == 0) out[0] = 0.f;
    cg::this_grid().sync();
    if (blockIdx.x < Bb)
        crf_batch(blockIdx.x, emis, labels, attn, trans, startt, endt, out);
}

// ---------------- fallback (non-cooperative) path ----------------
__global__ __launch_bounds__(256, 3) void k_emis(
    const float* __restrict__ hs, const float* __restrict__ W,
    const float* __restrict__ bvec, const float* __restrict__ cw,
    float* __restrict__ emis, float* __restrict__ out)
{
    if (blockIdx.x == 0 && threadIdx.x == 0) out[0] = 0.f;
    const int wave = blockIdx.x * 4 + (threadIdx.x >> 6);
    emis_phase(hs, W, bvec, cw, emis, wave, gridDim.x * 4);
}

__global__ __launch_bounds__(256) void k_crf(
    const float* __restrict__ emis, const int* __restrict__ labels,
    const int* __restrict__ attn, const float* __restrict__ trans,
    const float* __restrict__ startt, const float* __restrict__ endt,
    float* __restrict__ out)
{
    crf_batch(blockIdx.x, emis, labels, attn, trans, startt, endt, out);
}

extern "C" void kernel_launch(void* const* d_in, const int* in_sizes, int n_in,
                              void* d_out, int out_size, void* d_ws, size_t ws_size,
                              hipStream_t stream)
{
    const float* hs     = (const float*)d_in[0];
    const float* W      = (const float*)d_in[1];
    const float* bvec   = (const float*)d_in[2];
    const float* cw     = (const float*)d_in[3];
    const float* startt = (const float*)d_in[4];
    const float* endt   = (const float*)d_in[5];
    const float* trans  = (const float*)d_in[6];
    const int*   labels = (const int*)d_in[7];
    const int*   attn   = (const int*)d_in[8];
    float* out  = (float*)d_out;
    float* emis = (float*)d_ws;   // 64*512*9 floats

    void* args[] = {(void*)&hs, (void*)&W, (void*)&bvec, (void*)&cw,
                    (void*)&startt, (void*)&endt, (void*)&trans,
                    (void*)&labels, (void*)&attn, (void*)&emis, (void*)&out};
    // 768 blocks = 3 blocks/CU co-resident (LDS 27.6KB -> 5/CU, VGPR<=170 -> 3/CU)
    hipError_t err = hipLaunchCooperativeKernel((const void*)k_fused,
                                                dim3(768), dim3(256),
                                                args, (uint32_t)SMEM_BYTES, stream);
    if (err != hipSuccess) {
        hipLaunchKernelGGL(k_emis, dim3(2048), dim3(256), SMEM_BYTES, stream,
                           hs, W, bvec, cw, emis, out);
        hipLaunchKernelGGL(k_crf, dim3(Bb), dim3(256), SMEM_BYTES, stream,
                           emis, labels, attn, trans, startt, endt, out);
    }
}

// Round 8
// 145.039 us; speedup vs baseline: 1.0017x; 1.0017x over previous
//
#include <hip/hip_runtime.h>
#include <hip/hip_cooperative_groups.h>
#include <math.h>

#define Bb 64
#define Ss 512
#define Hh 768
#define Ll 9
#define CCH 16      // chunks per batch (CRF)
#define TCH 32      // steps per chunk
#define NROWS (Bb * Ss)       // 32768
#define NTILES (NROWS / 16)   // 2048 MFMA row-tiles
#define KSTEPS (Hh / 32)      // 24
#define SMEM_BYTES 27648

namespace cg = cooperative_groups;

typedef __attribute__((ext_vector_type(8))) short short8;   // 8 x bf16
typedef __attribute__((ext_vector_type(4))) float f32x4;

__device__ __forceinline__ ushort f2bf(float f) {           // RNE f32->bf16
    unsigned u = __float_as_uint(f);
    return (ushort)((u + 0x7FFFu + ((u >> 16) & 1u)) >> 16);
}

// ---------------- emissions phase: MFMA wave-per-16-row-tile ----------------
// A = hs rows (f32->bf16 in flight, coalesced float4 loads).
// B = W prepacked ONCE into LDS in fragment layout; 1 ds_read_b128 per K-step.
// Same (kg,j)->k packing on A and B => internal k-permutation cancels.
__device__ __forceinline__ void emis_phase(
    const float* __restrict__ hs, const float* __restrict__ W,
    const float* __restrict__ bvec, const float* __restrict__ cw,
    float* __restrict__ emis, int gwave)
{
    extern __shared__ char smem[];
    uint4* bpack = (uint4*)smem;     // [KSTEPS][64] fragments, 24576 B
    const int tid = threadIdx.x;

    // ---- pack B fragments (once per participating block) ----
    for (int slot = tid; slot < KSTEPS * 64; slot += 256) {
        const int s = slot >> 6, l = slot & 63;
        const int col = l & 15, kg = l >> 4;
        ushort h[8];
#pragma unroll
        for (int j = 0; j < 8; ++j) {
            const int k = s * 32 + kg * 8 + j;
            h[j] = (col < Ll) ? f2bf(W[k * Ll + col]) : (ushort)0;
        }
        uint4 u;
        u.x = (unsigned)h[0] | ((unsigned)h[1] << 16);
        u.y = (unsigned)h[2] | ((unsigned)h[3] << 16);
        u.z = (unsigned)h[4] | ((unsigned)h[5] << 16);
        u.w = (unsigned)h[6] | ((unsigned)h[7] << 16);
        bpack[slot] = u;
    }
    __syncthreads();

    if (gwave >= NTILES) return;

    const int lane = tid & 63;
    const int col = lane & 15, kg = lane >> 4;
    const int row0 = gwave * 16;
    const float* ap = hs + (size_t)(row0 + col) * Hh + kg * 8;

    // depth-3 software prefetch of A (2 float4 per iter per lane)
    float4 c0[3], c1[3];
#pragma unroll
    for (int p = 0; p < 3; ++p) {
        c0[p] = *(const float4*)(ap + p * 32);
        c1[p] = *(const float4*)(ap + p * 32 + 4);
    }
    f32x4 acc = {0.f, 0.f, 0.f, 0.f};
#pragma unroll
    for (int t = 0; t < KSTEPS; ++t) {
        const int sl = t % 3;
        const float4 a0 = c0[sl], a1 = c1[sl];
        if (t + 3 < KSTEPS) {
            c0[sl] = *(const float4*)(ap + (t + 3) * 32);
            c1[sl] = *(const float4*)(ap + (t + 3) * 32 + 4);
        }
        short8 a;
        a[0] = (short)f2bf(a0.x); a[1] = (short)f2bf(a0.y);
        a[2] = (short)f2bf(a0.z); a[3] = (short)f2bf(a0.w);
        a[4] = (short)f2bf(a1.x); a[5] = (short)f2bf(a1.y);
        a[6] = (short)f2bf(a1.z); a[7] = (short)f2bf(a1.w);
        const uint4 bu = bpack[t * 64 + lane];
        const short8 b = __builtin_bit_cast(short8, bu);
        acc = __builtin_amdgcn_mfma_f32_16x16x32_bf16(a, b, acc, 0, 0, 0);
    }
    // C/D: col = lane&15, row = (lane>>4)*4 + j   [guide-verified]
    if (col < Ll) {
        const float cwv = cw[col], bv = bvec[col];
#pragma unroll
        for (int j = 0; j < 4; ++j)
            emis[(size_t)(row0 + kg * 4 + j) * Ll + col] = (acc[j] + bv) * cwv;
    }
}

// ---------------- CRF phase for one batch (256 threads) ----------------
__device__ __forceinline__ void crf_batch(
    int b, const float* __restrict__ emis, const int* __restrict__ labels,
    const int* __restrict__ attn, const float* __restrict__ trans,
    const float* __restrict__ startt, const float* __restrict__ endt,
    float* __restrict__ out)
{
    extern __shared__ char smem[];
    int*   mkt_s    = (int*)smem;                  // 512 ints
    float* emis_s   = (float*)(smem + 2048);       // 4608 f
    float* trans_s  = (float*)(smem + 20480);      // 81 f
    float* et_s     = (float*)(smem + 20804);      // 81 f
    float* erow_s   = (float*)(smem + 21128);      // 1296 f
    float* rowmax_s = (float*)(smem + 26312);      // 144 f
    float* num_s    = (float*)(smem + 26888);      // 1 f

    const int tid = threadIdx.x;

#pragma unroll
    for (int it = 0; it < 2; ++it) {
        const int t = tid + it * 256;
        const int lab = labels[b * Ss + t];
        const int att = attn[b * Ss + t];
        const int tag = (lab == -100) ? 0 : lab;
        const int mk  = ((lab != -100) && (att == 1)) ? 1 : 0;
        mkt_s[t] = tag | (mk << 4);
    }
    {
        const float4* src = (const float4*)(emis + (size_t)b * Ss * Ll);
        float4* dst = (float4*)emis_s;
        for (int i = tid; i < (Ss * Ll) / 4; i += 256) dst[i] = src[i];
    }
    if (tid < Ll * Ll) {
        const float tv = trans[tid];
        trans_s[tid] = tv;
        et_s[tid] = __expf(tv);
    }
    __syncthreads();

    // ---- chunk workers: tid < 144 ----
    if (tid < CCH * Ll) {
        const int i = tid % Ll;
        const int c = tid / Ll;
        float et[Ll][Ll];
#pragma unroll
        for (int l = 0; l < Ll; ++l)
#pragma unroll
            for (int k = 0; k < Ll; ++k) et[l][k] = et_s[l * Ll + k];
        float vv[Ll];
#pragma unroll
        for (int l = 0; l < Ll; ++l) vv[l] = (l == i) ? 0.f : -1e30f;
        for (int s = (c == 0 ? 1 : 0); s < TCH; ++s) {
            const int t = c * TCH + s;
            const int mv = mkt_s[t];
            if (mv >> 4) {
                const float* e = emis_s + t * Ll;
                float m = vv[0];
#pragma unroll
                for (int l = 1; l < Ll; ++l) m = fmaxf(m, vv[l]);
                float p[Ll];
#pragma unroll
                for (int l = 0; l < Ll; ++l) p[l] = __expf(vv[l] - m);
                float nv[Ll];
#pragma unroll
                for (int k = 0; k < Ll; ++k) {
                    float sacc = 0.f;
#pragma unroll
                    for (int l = 0; l < Ll; ++l) sacc = fmaf(p[l], et[l][k], sacc);
                    nv[k] = m + __logf(sacc) + e[k];
                }
#pragma unroll
                for (int l = 0; l < Ll; ++l) vv[l] = nv[l];
            }
        }
        float m = vv[0];
#pragma unroll
        for (int l = 1; l < Ll; ++l) m = fmaxf(m, vv[l]);
        rowmax_s[c * Ll + i] = m;
#pragma unroll
        for (int l = 0; l < Ll; ++l)
            erow_s[(c * Ll + i) * Ll + l] = __expf(vv[l] - m);
    }

    // ---- numerator: wave 3 ----
    if (tid >= 192) {
        const int lane = tid - 192;
        float psum = 0.f;
        int pcnt = 0;
        for (int t = lane; t < Ss; t += 64) {
            const int mv  = mkt_s[t];
            const int tag = mv & 15;
            const bool mk = (mv >> 4) || (t == 0);
            if (t >= 1 && (mv >> 4)) {
                const int tagp = mkt_s[t - 1] & 15;
                psum += trans_s[tagp * Ll + tag] + emis_s[t * Ll + tag];
            }
            pcnt += mk ? 1 : 0;
        }
#pragma unroll
        for (int off = 32; off; off >>= 1) {
            psum += __shfl_xor(psum, off);
            pcnt += __shfl_xor(pcnt, off);
        }
        if (lane == 0) {
            const int tag0 = mkt_s[0] & 15;
            const int tagL = mkt_s[pcnt - 1] & 15;
            num_s[0] = startt[tag0] + emis_s[tag0] + psum + endt[tagL];
        }
    }
    __syncthreads();

    // ---- compose: lanes 0..8 of wave 0 ----
    if (tid < Ll) {
        const int lane = tid;
        float sc[Ll];
#pragma unroll
        for (int l = 0; l < Ll; ++l) sc[l] = startt[l] + emis_s[l];
        for (int c = 0; c < CCH; ++c) {
            float u[Ll];
#pragma unroll
            for (int l = 0; l < Ll; ++l) u[l] = sc[l] + rowmax_s[c * Ll + l];
            float M = u[0];
#pragma unroll
            for (int l = 1; l < Ll; ++l) M = fmaxf(M, u[l]);
            float sacc = 0.f;
#pragma unroll
            for (int l = 0; l < Ll; ++l)
                sacc = fmaf(__expf(u[l] - M), erow_s[(c * Ll + l) * Ll + lane], sacc);
            const float ns = M + __logf(sacc);
#pragma unroll
            for (int l = 0; l < Ll; ++l) sc[l] = __shfl(ns, l);
        }
        float M2 = sc[0] + endt[0];
#pragma unroll
        for (int l = 1; l < Ll; ++l) M2 = fmaxf(M2, sc[l] + endt[l]);
        float s2 = 0.f;
#pragma unroll
        for (int l = 0; l < Ll; ++l) s2 += __expf(sc[l] + endt[l] - M2);
        if (lane == 0) {
            const float logz = M2 + __logf(s2);
            atomicAdd(out, -(num_s[0] - logz) * (1.f / Bb));
        }
    }
}

// ---------------- single cooperative kernel ----------------
__global__ __launch_bounds__(256, 3) void k_fused(
    const float* __restrict__ hs, const float* __restrict__ W,
    const float* __restrict__ bvec, const float* __restrict__ cw,
    const float* __restrict__ startt, const float* __restrict__ endt,
    const float* __restrict__ trans, const int* __restrict__ labels,
    const int* __restrict__ attn, float* __restrict__ emis,
    float* __restrict__ out)
{
    if (blockIdx.x * 4 < NTILES) {
        const int gwave = blockIdx.x * 4 + (threadIdx.x >> 6);
        emis_phase(hs, W, bvec, cw, emis, gwave);
    }
    if (blockIdx.x == 0 && threadIdx.x == 0) out[0] = 0.f;
    cg::this_grid().sync();
    if (blockIdx.x < Bb)
        crf_batch(blockIdx.x, emis, labels, attn, trans, startt, endt, out);
}

// ---------------- fallback (non-cooperative) path ----------------
__global__ __launch_bounds__(256, 3) void k_emis(
    const float* __restrict__ hs, const float* __restrict__ W,
    const float* __restrict__ bvec, const float* __restrict__ cw,
    float* __restrict__ emis, float* __restrict__ out)
{
    if (blockIdx.x == 0 && threadIdx.x == 0) out[0] = 0.f;
    const int gwave = blockIdx.x * 4 + (threadIdx.x >> 6);
    emis_phase(hs, W, bvec, cw, emis, gwave);
}

__global__ __launch_bounds__(256) void k_crf(
    const float* __restrict__ emis, const int* __restrict__ labels,
    const int* __restrict__ attn, const float* __restrict__ trans,
    const float* __restrict__ startt, const float* __restrict__ endt,
    float* __restrict__ out)
{
    crf_batch(blockIdx.x, emis, labels, attn, trans, startt, endt, out);
}

extern "C" void kernel_launch(void* const* d_in, const int* in_sizes, int n_in,
                              void* d_out, int out_size, void* d_ws, size_t ws_size,
                              hipStream_t stream)
{
    const float* hs     = (const float*)d_in[0];
    const float* W      = (const float*)d_in[1];
    const float* bvec   = (const float*)d_in[2];
    const float* cw     = (const float*)d_in[3];
    const float* startt = (const float*)d_in[4];
    const float* endt   = (const float*)d_in[5];
    const float* trans  = (const float*)d_in[6];
    const int*   labels = (const int*)d_in[7];
    const int*   attn   = (const int*)d_in[8];
    float* out  = (float*)d_out;
    float* emis = (float*)d_ws;   // 64*512*9 floats

    void* args[] = {(void*)&hs, (void*)&W, (void*)&bvec, (void*)&cw,
                    (void*)&startt, (void*)&endt, (void*)&trans,
                    (void*)&labels, (void*)&attn, (void*)&emis, (void*)&out};
    // 768 blocks = 3 blocks/CU co-resident (LDS 27.6KB*3, VGPR<=170)
    hipError_t err = hipLaunchCooperativeKernel((const void*)k_fused,
                                                dim3(768), dim3(256),
                                                args, (uint32_t)SMEM_BYTES, stream);
    if (err != hipSuccess) {
        hipLaunchKernelGGL(k_emis, dim3(512), dim3(256), SMEM_BYTES, stream,
                           hs, W, bvec, cw, emis, out);
        hipLaunchKernelGGL(k_crf, dim3(Bb), dim3(256), SMEM_BYTES, stream,
                           emis, labels, attn, trans, startt, endt, out);
    }
}

// Round 9
// 56.398 us; speedup vs baseline: 2.5761x; 2.5717x over previous
//
#include <hip/hip_runtime.h>
#include <math.h>

#define Bb 64
#define Ss 512
#define Hh 768
#define Ll 9
#define CCH 16      // chunks per batch (CRF)
#define TCH 32      // steps per chunk
#define NROWS (Bb * Ss)       // 32768
#define NTILES (NROWS / 16)   // 2048 MFMA row-tiles
#define KSTEPS (Hh / 32)      // 24
#define EMIS_SMEM 24576       // B-pack fragments
#define CRF_SMEM  27648       // CRF arrays

typedef __attribute__((ext_vector_type(8))) short short8;   // 8 x bf16
typedef __attribute__((ext_vector_type(4))) float f32x4;

__device__ __forceinline__ ushort f2bf(float f) {           // RNE f32->bf16
    unsigned u = __float_as_uint(f);
    return (ushort)((u + 0x7FFFu + ((u >> 16) & 1u)) >> 16);
}

// ---------------- K1: MFMA emissions, wave-per-16-row-tile ----------------
// A = hs rows (f32->bf16 in flight, coalesced float4 loads).
// B = W prepacked ONCE into LDS in fragment layout; 1 ds_read_b128 per K-step.
// Same (kg,j)->k packing on A and B => internal k-permutation cancels.
__global__ __launch_bounds__(256) void k_emis(
    const float* __restrict__ hs, const float* __restrict__ W,
    const float* __restrict__ bvec, const float* __restrict__ cw,
    float* __restrict__ emis, float* __restrict__ out)
{
    extern __shared__ char smem[];
    uint4* bpack = (uint4*)smem;     // [KSTEPS][64] fragments, 24576 B
    const int tid = threadIdx.x;

    if (blockIdx.x == 0 && tid == 0) out[0] = 0.f;   // k_crf runs after in-stream

    // ---- pack B fragments (once per block) ----
    for (int slot = tid; slot < KSTEPS * 64; slot += 256) {
        const int s = slot >> 6, l = slot & 63;
        const int col = l & 15, kg = l >> 4;
        ushort h[8];
#pragma unroll
        for (int j = 0; j < 8; ++j) {
            const int k = s * 32 + kg * 8 + j;
            h[j] = (col < Ll) ? f2bf(W[k * Ll + col]) : (ushort)0;
        }
        uint4 u;
        u.x = (unsigned)h[0] | ((unsigned)h[1] << 16);
        u.y = (unsigned)h[2] | ((unsigned)h[3] << 16);
        u.z = (unsigned)h[4] | ((unsigned)h[5] << 16);
        u.w = (unsigned)h[6] | ((unsigned)h[7] << 16);
        bpack[slot] = u;
    }
    __syncthreads();

    const int gwave = blockIdx.x * 4 + (tid >> 6);
    if (gwave >= NTILES) return;

    const int lane = tid & 63;
    const int col = lane & 15, kg = lane >> 4;
    const int row0 = gwave * 16;
    const float* ap = hs + (size_t)(row0 + col) * Hh + kg * 8;

    // depth-3 software prefetch of A (2 float4 per iter per lane)
    float4 c0[3], c1[3];
#pragma unroll
    for (int p = 0; p < 3; ++p) {
        c0[p] = *(const float4*)(ap + p * 32);
        c1[p] = *(const float4*)(ap + p * 32 + 4);
    }
    f32x4 acc = {0.f, 0.f, 0.f, 0.f};
#pragma unroll
    for (int t = 0; t < KSTEPS; ++t) {
        const int sl = t % 3;
        const float4 a0 = c0[sl], a1 = c1[sl];
        if (t + 3 < KSTEPS) {
            c0[sl] = *(const float4*)(ap + (t + 3) * 32);
            c1[sl] = *(const float4*)(ap + (t + 3) * 32 + 4);
        }
        short8 a;
        a[0] = (short)f2bf(a0.x); a[1] = (short)f2bf(a0.y);
        a[2] = (short)f2bf(a0.z); a[3] = (short)f2bf(a0.w);
        a[4] = (short)f2bf(a1.x); a[5] = (short)f2bf(a1.y);
        a[6] = (short)f2bf(a1.z); a[7] = (short)f2bf(a1.w);
        const uint4 bu = bpack[t * 64 + lane];
        const short8 b = __builtin_bit_cast(short8, bu);
        acc = __builtin_amdgcn_mfma_f32_16x16x32_bf16(a, b, acc, 0, 0, 0);
    }
    // C/D: col = lane&15, row = (lane>>4)*4 + j   [guide-verified]
    if (col < Ll) {
        const float cwv = cw[col], bv = bvec[col];
#pragma unroll
        for (int j = 0; j < 4; ++j)
            emis[(size_t)(row0 + kg * 4 + j) * Ll + col] = (acc[j] + bv) * cwv;
    }
}

// ---------------- K2: fused CRF per batch (256 threads) ----------------
__global__ __launch_bounds__(256) void k_crf(
    const float* __restrict__ emis, const int* __restrict__ labels,
    const int* __restrict__ attn, const float* __restrict__ trans,
    const float* __restrict__ startt, const float* __restrict__ endt,
    float* __restrict__ out)
{
    extern __shared__ char smem[];
    int*   mkt_s    = (int*)smem;                  // 512 ints
    float* emis_s   = (float*)(smem + 2048);       // 4608 f
    float* trans_s  = (float*)(smem + 20480);      // 81 f
    float* et_s     = (float*)(smem + 20804);      // 81 f
    float* erow_s   = (float*)(smem + 21128);      // 1296 f
    float* rowmax_s = (float*)(smem + 26312);      // 144 f
    float* num_s    = (float*)(smem + 26888);      // 1 f

    const int b   = blockIdx.x;
    const int tid = threadIdx.x;

#pragma unroll
    for (int it = 0; it < 2; ++it) {
        const int t = tid + it * 256;
        const int lab = labels[b * Ss + t];
        const int att = attn[b * Ss + t];
        const int tag = (lab == -100) ? 0 : lab;
        const int mk  = ((lab != -100) && (att == 1)) ? 1 : 0;
        mkt_s[t] = tag | (mk << 4);
    }
    {
        const float4* src = (const float4*)(emis + (size_t)b * Ss * Ll);
        float4* dst = (float4*)emis_s;
        for (int i = tid; i < (Ss * Ll) / 4; i += 256) dst[i] = src[i];
    }
    if (tid < Ll * Ll) {
        const float tv = trans[tid];
        trans_s[tid] = tv;
        et_s[tid] = __expf(tv);
    }
    __syncthreads();

    // ---- chunk workers: tid < 144; row i of chunk c's 9x9 transfer matrix ----
    if (tid < CCH * Ll) {
        const int i = tid % Ll;
        const int c = tid / Ll;
        float et[Ll][Ll];
#pragma unroll
        for (int l = 0; l < Ll; ++l)
#pragma unroll
            for (int k = 0; k < Ll; ++k) et[l][k] = et_s[l * Ll + k];
        float vv[Ll];
#pragma unroll
        for (int l = 0; l < Ll; ++l) vv[l] = (l == i) ? 0.f : -1e30f;
        for (int s = (c == 0 ? 1 : 0); s < TCH; ++s) {
            const int t = c * TCH + s;
            const int mv = mkt_s[t];
            if (mv >> 4) {
                const float* e = emis_s + t * Ll;
                float m = vv[0];
#pragma unroll
                for (int l = 1; l < Ll; ++l) m = fmaxf(m, vv[l]);
                float p[Ll];
#pragma unroll
                for (int l = 0; l < Ll; ++l) p[l] = __expf(vv[l] - m);
                float nv[Ll];
#pragma unroll
                for (int k = 0; k < Ll; ++k) {
                    float sacc = 0.f;
#pragma unroll
                    for (int l = 0; l < Ll; ++l) sacc = fmaf(p[l], et[l][k], sacc);
                    nv[k] = m + __logf(sacc) + e[k];
                }
#pragma unroll
                for (int l = 0; l < Ll; ++l) vv[l] = nv[l];
            }
        }
        float m = vv[0];
#pragma unroll
        for (int l = 1; l < Ll; ++l) m = fmaxf(m, vv[l]);
        rowmax_s[c * Ll + i] = m;
#pragma unroll
        for (int l = 0; l < Ll; ++l)
            erow_s[(c * Ll + i) * Ll + l] = __expf(vv[l] - m);
    }

    // ---- numerator: wave 3 (tid 192..255) ----
    if (tid >= 192) {
        const int lane = tid - 192;
        float psum = 0.f;
        int pcnt = 0;
        for (int t = lane; t < Ss; t += 64) {
            const int mv  = mkt_s[t];
            const int tag = mv & 15;
            const bool mk = (mv >> 4) || (t == 0);
            if (t >= 1 && (mv >> 4)) {
                const int tagp = mkt_s[t - 1] & 15;
                psum += trans_s[tagp * Ll + tag] + emis_s[t * Ll + tag];
            }
            pcnt += mk ? 1 : 0;
        }
#pragma unroll
        for (int off = 32; off; off >>= 1) {
            psum += __shfl_xor(psum, off);
            pcnt += __shfl_xor(pcnt, off);
        }
        if (lane == 0) {
            const int tag0 = mkt_s[0] & 15;
            const int tagL = mkt_s[pcnt - 1] & 15;
            num_s[0] = startt[tag0] + emis_s[tag0] + psum + endt[tagL];
        }
    }
    __syncthreads();

    // ---- compose: lanes 0..8 of wave 0 (lane k owns column k) ----
    if (tid < Ll) {
        const int lane = tid;
        float sc[Ll];
#pragma unroll
        for (int l = 0; l < Ll; ++l) sc[l] = startt[l] + emis_s[l];
        for (int c = 0; c < CCH; ++c) {
            float u[Ll];
#pragma unroll
            for (int l = 0; l < Ll; ++l) u[l] = sc[l] + rowmax_s[c * Ll + l];
            float M = u[0];
#pragma unroll
            for (int l = 1; l < Ll; ++l) M = fmaxf(M, u[l]);
            float sacc = 0.f;
#pragma unroll
            for (int l = 0; l < Ll; ++l)
                sacc = fmaf(__expf(u[l] - M), erow_s[(c * Ll + l) * Ll + lane], sacc);
            const float ns = M + __logf(sacc);
#pragma unroll
            for (int l = 0; l < Ll; ++l) sc[l] = __shfl(ns, l);
        }
        float M2 = sc[0] + endt[0];
#pragma unroll
        for (int l = 1; l < Ll; ++l) M2 = fmaxf(M2, sc[l] + endt[l]);
        float s2 = 0.f;
#pragma unroll
        for (int l = 0; l < Ll; ++l) s2 += __expf(sc[l] + endt[l] - M2);
        if (lane == 0) {
            const float logz = M2 + __logf(s2);
            atomicAdd(out, -(num_s[0] - logz) * (1.f / Bb));
        }
    }
}

extern "C" void kernel_launch(void* const* d_in, const int* in_sizes, int n_in,
                              void* d_out, int out_size, void* d_ws, size_t ws_size,
                              hipStream_t stream)
{
    const float* hs     = (const float*)d_in[0];
    const float* W      = (const float*)d_in[1];
    const float* bvec   = (const float*)d_in[2];
    const float* cw     = (const float*)d_in[3];
    const float* startt = (const float*)d_in[4];
    const float* endt   = (const float*)d_in[5];
    const float* trans  = (const float*)d_in[6];
    const int*   labels = (const int*)d_in[7];
    const int*   attn   = (const int*)d_in[8];
    float* out  = (float*)d_out;
    float* emis = (float*)d_ws;   // 64*512*9 floats

    hipLaunchKernelGGL(k_emis, dim3(NTILES / 4), dim3(256), EMIS_SMEM, stream,
                       hs, W, bvec, cw, emis, out);
    hipLaunchKernelGGL(k_crf, dim3(Bb), dim3(256), CRF_SMEM, stream,
                       emis, labels, attn, trans, startt, endt, out);
}